// Round 13
// baseline (108.155 us; speedup 1.0000x reference)
//
#include <hip/hip_runtime.h>

typedef __bf16 bf16x8 __attribute__((ext_vector_type(8)));
typedef float  f32x4  __attribute__((ext_vector_type(4)));

#define IC    256
#define OC    256
#define Hh    64
#define Ww    64
#define Bb    16
#define DLEN  512
#define KKTOT 2304        // IC*9
#define HP    66          // padded spatial
#define MODSCALE 0.0625f                 // sqrt(2/512)
#define WSCALE   0.029462782549439484f   // sqrt(2/2304)

// workspace layout (bytes)
#define XT_ELEMS  (Bb*HP*HP*IC)          // 17,842,176 bf16
#define XT_BYTES  (XT_ELEMS*2)           // 35,684,352
#define WMAT_OFF  XT_BYTES
#define WMAT_BYTES (OC*KKTOT*2)          // 1,179,648
#define S_OFF     (WMAT_OFF + WMAT_BYTES)

typedef const __attribute__((address_space(1))) unsigned int* gptr_t;
typedef __attribute__((address_space(3))) unsigned int* lptr_t;

__device__ __forceinline__ void gl2lds16(const void* g, void* l) {
  __builtin_amdgcn_global_load_lds((gptr_t)g, (lptr_t)l, 16, 0, 0);
}

// ---------------- merged prep: blocks 0..255 = wmat(+demod), 256..271 = style
__global__ void k_prep(const float* __restrict__ wt,
                       const float* __restrict__ style,
                       const float* __restrict__ mw,
                       __bf16* __restrict__ wmat,
                       float* __restrict__ s_out) {
  const int t = threadIdx.x;
  if (blockIdx.x >= 256) {
    const int b = blockIdx.x - 256;
    __shared__ float st[DLEN];
    st[t]       = style[b*DLEN + t];
    st[t + 256] = style[b*DLEN + t + 256];
    __syncthreads();
    const float4* mwr = (const float4*)(mw + (long)t*DLEN);
    float acc = 0.f;
    #pragma unroll 4
    for (int d = 0; d < DLEN/4; ++d) {
      float4 v = mwr[d];
      acc += v.x*st[d*4] + v.y*st[d*4+1] + v.z*st[d*4+2] + v.w*st[d*4+3];
    }
    s_out[b*IC + t] = acc * MODSCALE;
    return;
  }
  const int oc = blockIdx.x;
  float w9[9];
  const float* p = wt + ((long)oc*IC + t)*9;
  float ss = 0.f;
  #pragma unroll
  for (int r = 0; r < 9; ++r) { w9[r] = p[r]; ss += w9[r]*w9[r]; }
  #pragma unroll
  for (int off = 32; off; off >>= 1) ss += __shfl_down(ss, off, 64);
  __shared__ float red[4];
  if ((t & 63) == 0) red[t >> 6] = ss;
  __syncthreads();
  float total = red[0] + red[1] + red[2] + red[3];
  float dm = WSCALE / sqrtf(total + 1e-8f);
  #pragma unroll
  for (int r = 0; r < 9; ++r)
    wmat[oc*KKTOT + r*IC + t] = (__bf16)(w9[r] * dm);
}

// ---------------- xt[b][y+1][x+1][ic] = bf16(image[b][ic][y][x] * s[b][ic]) (NHWC, padded)
// blocks >= Bb*256 zero the halo of batch (blockIdx.x - Bb*256); writes disjoint.
__global__ void k_xmod(const float* __restrict__ img,
                       const float* __restrict__ s,
                       __bf16* __restrict__ xt) {
  const int t = threadIdx.x;
  if (blockIdx.x >= Bb*256) {
    const int b = blockIdx.x - Bb*256;
    uint4* base = (uint4*)(xt + (long)b*HP*HP*IC);
    const uint4 z = {0u,0u,0u,0u};
    for (int i = t; i < 2112; i += 256) { base[i] = z; base[137280 + i] = z; }
    for (int i = t; i < 64*32; i += 256) {
      int y = 1 + (i >> 5), c = i & 31;
      base[y*2112 + c] = z;
      base[y*2112 + 2080 + c] = z;
    }
    return;
  }
  __shared__ float tile[64][69];
  const int b   = blockIdx.x >> 8;
  const int rem = blockIdx.x & 255;
  const int y   = rem >> 2;          // source row 0..63
  const int ic0 = (rem & 3) << 6;    // ic block of 64
  #pragma unroll
  for (int r = 0; r < 4; ++r) {
    int seg = r*256 + t;
    int i   = seg >> 4;              // ic offset 0..63
    int x0  = (seg & 15) * 4;
    float4 v = *(const float4*)(img + (((long)(b*IC + ic0 + i)*Hh + y)*Ww + x0));
    float sv = s[b*IC + ic0 + i];
    tile[i][x0+0] = v.x*sv; tile[i][x0+1] = v.y*sv;
    tile[i][x0+2] = v.z*sv; tile[i][x0+3] = v.w*sv;
  }
  __syncthreads();
  const int x  = t >> 2;
  const int j0 = (t & 3) << 4;
  bf16x8 o0, o1;
  #pragma unroll
  for (int e = 0; e < 8; ++e) o0[e] = (__bf16)tile[j0 + e][x];
  #pragma unroll
  for (int e = 0; e < 8; ++e) o1[e] = (__bf16)tile[j0 + 8 + e][x];
  __bf16* dst = xt + (((long)(b*HP + y + 1)*HP + (x + 1))*IC + ic0 + j0);
  ((bf16x8*)dst)[0] = o0;
  ((bf16x8*)dst)[1] = o1;
}

// ---------------- 256x256x64 implicit-GEMM conv, CROSS-BARRIER B READ-AHEAD
// A double-buffered (dist 1, 2x32K @0/32K). B TRIPLE-buffered (dist 2,
// 3x32K @64K+slot*32K): tile t+1's B-frags are read from LDS DURING tile t's
// last MFMA clusters (slot (t+1)%3 was staged in t-1, drained at t-1's sync),
// so every wave crosses the barrier with B already in registers. One
// __syncthreads per tile. Race-derivation in r13 notes: slot(t-1)'s last read
// is in tile t-2; restaged in tile t -> two barriers apart.
__global__ __launch_bounds__(512, 1) void k_conv(const __bf16* __restrict__ wmat,
                                                 const __bf16* __restrict__ xt,
                                                 float* __restrict__ out) {
  __shared__ __attribute__((aligned(128))) char ldsc[163840]; // A 2x32K | B 3x32K
  const int tid  = threadIdx.x;
  const int lane = tid & 63;
  const int wv   = tid >> 6;
  const int wr   = wv >> 2;            // 0..1  (M group, 128 rows)
  const int wc   = wv & 3;             // 0..3  (N group, 64 cols)

  // bijective XCD remap
  const int bi     = blockIdx.x;
  const int b      = ((bi & 7) << 1) | ((bi >> 7) & 1);
  const int hwBase = ((bi >> 3) & 15) << 8;

  // ---- staging precompute (2 x 16B loads per thread per half-tile)
  const int row0 = tid >> 3;                    // 0..63
  const int c8   = (tid & 7) ^ (row0 & 7);      // pre-swizzled 16B-chunk col
  const long aOff0 = (long)row0*KKTOT + c8*8;
  const long aOff1 = aOff0 + (long)64*KKTOT;
  const int x  = row0;
  const int y0 = hwBase >> 6;
  long bOff[2][2];
  #pragma unroll
  for (int h = 0; h < 2; ++h)
    #pragma unroll
    for (int l = 0; l < 2; ++l)
      bOff[h][l] = (((long)b*HP + y0 + 2*h + l)*HP + x)*IC + c8*8;
  const unsigned wvOff = wv << 10;

#define STAGE_A(tt, h) do {                                              \
    char* d_ = ldsc + (((tt)&1)<<15) + ((h)<<14) + wvOff;                \
    const __bf16* g_ = wmat + (h)*(128*KKTOT) + (tt)*64;                 \
    gl2lds16(g_ + aOff0, d_);                                            \
    gl2lds16(g_ + aOff1, d_ + 8192);                                     \
  } while (0)

#define STAGE_B(tt, h, sb) do {                                          \
    char* d_ = ldsc + 65536 + ((tt)%3)*32768 + ((h)<<14) + wvOff;        \
    gl2lds16(xt + bOff[h][0] + (sb), d_);                                 \
    gl2lds16(xt + bOff[h][1] + (sb), d_ + 8192);                          \
  } while (0)

  f32x4 acc[8][4] = {};
  bf16x8 af[2][2];               // single A quadrant set (WAR ok: r5 mode)
  bf16x8 bfrA[4][2], bfrB[4][2]; // B register dbuf across tiles (static names)
  const int cb = (lane >> 4) << 4;
  const int rA = wr*128 + (lane & 15);
  const int rB = wc*64  + (lane & 15);

#define READ_A(q) do {                                                   \
    _Pragma("unroll")                                                    \
    for (int m2 = 0; m2 < 2; ++m2) {                                     \
      int rr = rA + (q)*32 + m2*16, sw = (rr & 7) << 4;                  \
      af[m2][0] = *(const bf16x8*)(Abuf + rr*128 + ((  0 + cb) ^ sw));   \
      af[m2][1] = *(const bf16x8*)(Abuf + rr*128 + (( 64 + cb) ^ sw));   \
    }                                                                    \
  } while (0)

#define READ_B_TO(BF, BP) do {                                           \
    _Pragma("unroll")                                                    \
    for (int n = 0; n < 4; ++n) {                                        \
      int rr = rB + n*16, sw = (rr & 7) << 4;                            \
      BF[n][0] = *(const bf16x8*)((BP) + rr*128 + ((  0 + cb) ^ sw));    \
      BF[n][1] = *(const bf16x8*)((BP) + rr*128 + (( 64 + cb) ^ sw));    \
    }                                                                    \
  } while (0)

#define MFMA_Q(q, BF) do {                                               \
    __builtin_amdgcn_s_setprio(1);                                       \
    _Pragma("unroll")                                                    \
    for (int ks = 0; ks < 2; ++ks)                                       \
      _Pragma("unroll")                                                  \
      for (int m2 = 0; m2 < 2; ++m2)                                     \
        _Pragma("unroll")                                                \
        for (int n = 0; n < 4; ++n)                                      \
          acc[(q)*2+m2][n] = __builtin_amdgcn_mfma_f32_16x16x32_bf16(af[m2][ks], BF[n][ks], acc[(q)*2+m2][n], 0, 0, 0); \
    __builtin_amdgcn_s_setprio(0);                                       \
  } while (0)

// Tile body: A q-reads slide under MFMA stream; B(t+1) frags read under Q2/Q3.
#define TILE(t_, CUR, NXT) do {                                          \
    char* Abuf = ldsc + (((t_) & 1) << 15);                              \
    const char* Bnxt = ldsc + 65536 + (((t_)+1)%3)*32768;                \
    const int t2 = (t_) + 2, pos2 = t2 >> 2, kh2 = pos2/3;               \
    const int sb2 = (kh2*HP + (pos2 - kh2*3))*IC + ((t2 & 3) << 6);      \
    READ_A(0);                                                           \
    if ((t_) < 35) { STAGE_A((t_)+1, 0); STAGE_A((t_)+1, 1); }           \
    if ((t_) < 34) { STAGE_B(t2, 0, sb2); STAGE_B(t2, 1, sb2); }         \
    MFMA_Q(0, CUR);                                                      \
    READ_A(1);                                                           \
    MFMA_Q(1, CUR);                                                      \
    READ_A(2);                                                           \
    MFMA_Q(2, CUR);                                                      \
    READ_A(3);                                                           \
    if ((t_) < 35) READ_B_TO(NXT, Bnxt);                                 \
    MFMA_Q(3, CUR);                                                      \
    __syncthreads();                                                     \
  } while (0)

  // ---- prologue: A(0); B(0)->slot0, B(1)->slot1; sync; pre-read B(0)
  STAGE_A(0, 0); STAGE_A(0, 1);
  STAGE_B(0, 0, 0); STAGE_B(0, 1, 0);
  {
    const int tt = 1, pos = tt >> 2, kh = pos/3;
    const int sb1 = (kh*HP + (pos - kh*3))*IC + ((tt & 3) << 6);
    STAGE_B(1, 0, sb1); STAGE_B(1, 1, sb1);
  }
  __syncthreads();
  READ_B_TO(bfrA, ldsc + 65536);

  for (int tp = 0; tp < 18; ++tp) {
    const int t0 = tp * 2;
    TILE(t0,     bfrA, bfrB);
    TILE(t0 + 1, bfrB, bfrA);
  }

  // ---- epilogue: f32 stores, 16-lane 64B segments
  float* outb = out + (((long)b*OC + wr*128 + ((lane >> 4) << 2))*(Hh*Ww))
                    + hwBase + wc*64 + (lane & 15);
  #pragma unroll
  for (int m = 0; m < 8; ++m)
    #pragma unroll
    for (int n = 0; n < 4; ++n)
      #pragma unroll
      for (int j = 0; j < 4; ++j)
        outb[((long)(m*16 + j))*(Hh*Ww) + n*16] = acc[m][n][j];
}

extern "C" void kernel_launch(void* const* d_in, const int* in_sizes, int n_in,
                              void* d_out, int out_size, void* d_ws, size_t ws_size,
                              hipStream_t stream) {
  const float* image = (const float*)d_in[0];
  const float* style = (const float*)d_in[1];
  const float* weight= (const float*)d_in[2];
  const float* modw  = (const float*)d_in[3];
  float* out = (float*)d_out;

  char* ws = (char*)d_ws;
  __bf16* xt   = (__bf16*)ws;
  __bf16* wmat = (__bf16*)(ws + WMAT_OFF);
  float*  sbuf = (float*)(ws + S_OFF);

  k_prep<<<272, 256, 0, stream>>>(weight, style, modw, wmat, sbuf);
  k_xmod<<<Bb*256 + Bb, 256, 0, stream>>>(image, sbuf, xt);
  k_conv<<<256, 512, 0, stream>>>(wmat, xt, out);
}

// Round 14
// 103.668 us; speedup vs baseline: 1.0433x; 1.0433x over previous
//
#include <hip/hip_runtime.h>

typedef __bf16 bf16x8 __attribute__((ext_vector_type(8)));
typedef float  f32x4  __attribute__((ext_vector_type(4)));

#define IC    256
#define OC    256
#define Hh    64
#define Ww    64
#define Bb    16
#define DLEN  512
#define KKTOT 2304        // IC*9
#define HP    66          // padded spatial
#define MODSCALE 0.0625f                 // sqrt(2/512)
#define WSCALE   0.029462782549439484f   // sqrt(2/2304)

// workspace layout (bytes)
#define XT_ELEMS  (Bb*HP*HP*IC)          // 17,842,176 bf16
#define XT_BYTES  (XT_ELEMS*2)           // 35,684,352
#define WMAT_OFF  XT_BYTES
#define WMAT_BYTES (OC*KKTOT*2)          // 1,179,648
#define S_OFF     (WMAT_OFF + WMAT_BYTES)

typedef const __attribute__((address_space(1))) unsigned int* gptr_t;
typedef __attribute__((address_space(3))) unsigned int* lptr_t;

__device__ __forceinline__ void gl2lds16(const void* g, void* l) {
  __builtin_amdgcn_global_load_lds((gptr_t)g, (lptr_t)l, 16, 0, 0);
}

// ---------------- merged prep: blocks 0..255 = wmat(+demod), 256..271 = style
__global__ void k_prep(const float* __restrict__ wt,
                       const float* __restrict__ style,
                       const float* __restrict__ mw,
                       __bf16* __restrict__ wmat,
                       float* __restrict__ s_out) {
  const int t = threadIdx.x;
  if (blockIdx.x >= 256) {
    const int b = blockIdx.x - 256;
    __shared__ float st[DLEN];
    st[t]       = style[b*DLEN + t];
    st[t + 256] = style[b*DLEN + t + 256];
    __syncthreads();
    const float4* mwr = (const float4*)(mw + (long)t*DLEN);
    float acc = 0.f;
    #pragma unroll 4
    for (int d = 0; d < DLEN/4; ++d) {
      float4 v = mwr[d];
      acc += v.x*st[d*4] + v.y*st[d*4+1] + v.z*st[d*4+2] + v.w*st[d*4+3];
    }
    s_out[b*IC + t] = acc * MODSCALE;
    return;
  }
  const int oc = blockIdx.x;
  float w9[9];
  const float* p = wt + ((long)oc*IC + t)*9;
  float ss = 0.f;
  #pragma unroll
  for (int r = 0; r < 9; ++r) { w9[r] = p[r]; ss += w9[r]*w9[r]; }
  #pragma unroll
  for (int off = 32; off; off >>= 1) ss += __shfl_down(ss, off, 64);
  __shared__ float red[4];
  if ((t & 63) == 0) red[t >> 6] = ss;
  __syncthreads();
  float total = red[0] + red[1] + red[2] + red[3];
  float dm = WSCALE / sqrtf(total + 1e-8f);
  #pragma unroll
  for (int r = 0; r < 9; ++r)
    wmat[oc*KKTOT + r*IC + t] = (__bf16)(w9[r] * dm);
}

// ---------------- xt[b][y+1][x+1][ic] = bf16(image[b][ic][y][x] * s[b][ic]) (NHWC, padded)
// blocks >= Bb*256 zero the halo of batch (blockIdx.x - Bb*256); writes disjoint.
__global__ void k_xmod(const float* __restrict__ img,
                       const float* __restrict__ s,
                       __bf16* __restrict__ xt) {
  const int t = threadIdx.x;
  if (blockIdx.x >= Bb*256) {
    const int b = blockIdx.x - Bb*256;
    uint4* base = (uint4*)(xt + (long)b*HP*HP*IC);
    const uint4 z = {0u,0u,0u,0u};
    for (int i = t; i < 2112; i += 256) { base[i] = z; base[137280 + i] = z; }
    for (int i = t; i < 64*32; i += 256) {
      int y = 1 + (i >> 5), c = i & 31;
      base[y*2112 + c] = z;
      base[y*2112 + 2080 + c] = z;
    }
    return;
  }
  __shared__ float tile[64][69];
  const int b   = blockIdx.x >> 8;
  const int rem = blockIdx.x & 255;
  const int y   = rem >> 2;          // source row 0..63
  const int ic0 = (rem & 3) << 6;    // ic block of 64
  #pragma unroll
  for (int r = 0; r < 4; ++r) {
    int seg = r*256 + t;
    int i   = seg >> 4;              // ic offset 0..63
    int x0  = (seg & 15) * 4;
    float4 v = *(const float4*)(img + (((long)(b*IC + ic0 + i)*Hh + y)*Ww + x0));
    float sv = s[b*IC + ic0 + i];
    tile[i][x0+0] = v.x*sv; tile[i][x0+1] = v.y*sv;
    tile[i][x0+2] = v.z*sv; tile[i][x0+3] = v.w*sv;
  }
  __syncthreads();
  const int x  = t >> 2;
  const int j0 = (t & 3) << 4;
  bf16x8 o0, o1;
  #pragma unroll
  for (int e = 0; e < 8; ++e) o0[e] = (__bf16)tile[j0 + e][x];
  #pragma unroll
  for (int e = 0; e < 8; ++e) o1[e] = (__bf16)tile[j0 + 8 + e][x];
  __bf16* dst = xt + (((long)(b*HP + y + 1)*HP + (x + 1))*IC + ic0 + j0);
  ((bf16x8*)dst)[0] = o0;
  ((bf16x8*)dst)[1] = o1;
}

// ---------------- 256x256x64 implicit-GEMM conv (r8 structure = proven 75us)
// single __syncthreads per K-tile, ping-pong A-frag register sets, NO setprio
// (m190: setprio hurts single-phase lockstep GEMM; only pays on phase-split).
__global__ __launch_bounds__(512, 2) void k_conv(const __bf16* __restrict__ wmat,
                                                 const __bf16* __restrict__ xt,
                                                 float* __restrict__ out) {
  __shared__ __attribute__((aligned(128))) char ldsc[131072]; // 2 bufs x (A 32K | B 32K)
  const int tid  = threadIdx.x;
  const int lane = tid & 63;
  const int wv   = tid >> 6;
  const int wr   = wv >> 2;            // 0..1  (M group, 128 rows)
  const int wc   = wv & 3;             // 0..3  (N group, 64 cols)

  // bijective XCD remap
  const int bi     = blockIdx.x;
  const int b      = ((bi & 7) << 1) | ((bi >> 7) & 1);
  const int hwBase = ((bi >> 3) & 15) << 8;

  // ---- staging precompute (2 x 16B loads per thread per half-tile)
  const int row0 = tid >> 3;                    // 0..63
  const int c8   = (tid & 7) ^ (row0 & 7);      // pre-swizzled 16B-chunk col
  const long aOff0 = (long)row0*KKTOT + c8*8;
  const long aOff1 = aOff0 + (long)64*KKTOT;
  const int x  = row0;
  const int y0 = hwBase >> 6;
  long bOff[2][2];
  #pragma unroll
  for (int h = 0; h < 2; ++h)
    #pragma unroll
    for (int l = 0; l < 2; ++l)
      bOff[h][l] = (((long)b*HP + y0 + 2*h + l)*HP + x)*IC + c8*8;
  const unsigned wvOff = wv << 10;

#define STAGE_A(tt, h) do {                                              \
    char* d_ = ldsc + (((tt)&1)<<16) + ((h)<<14) + wvOff;                \
    const __bf16* g_ = wmat + (h)*(128*KKTOT) + (tt)*64;                 \
    gl2lds16(g_ + aOff0, d_);                                            \
    gl2lds16(g_ + aOff1, d_ + 8192);                                     \
  } while (0)

#define STAGE_B(tt, h, sb) do {                                          \
    char* d_ = ldsc + (((tt)&1)<<16) + 32768 + ((h)<<14) + wvOff;        \
    gl2lds16(xt + bOff[h][0] + (sb), d_);                                 \
    gl2lds16(xt + bOff[h][1] + (sb), d_ + 8192);                          \
  } while (0)

  // ---- prologue: tile 0 (parity 0), sb=0
  STAGE_A(0, 0); STAGE_A(0, 1);
  STAGE_B(0, 0, 0); STAGE_B(0, 1, 0);
  __syncthreads();

  f32x4 acc[8][4] = {};
  bf16x8 af0[2][2], af1[2][2];   // ping-pong A quadrant sets (static idx)
  bf16x8 bfr[4][2];
  const int cb = (lane >> 4) << 4;
  const int rA = wr*128 + (lane & 15);
  const int rB = wc*64  + (lane & 15);

#define READ_A_TO(AF, q) do {                                            \
    _Pragma("unroll")                                                    \
    for (int m2 = 0; m2 < 2; ++m2) {                                     \
      int rr = rA + (q)*32 + m2*16, sw = (rr & 7) << 4;                  \
      AF[m2][0] = *(const bf16x8*)(Abuf + rr*128 + ((  0 + cb) ^ sw));   \
      AF[m2][1] = *(const bf16x8*)(Abuf + rr*128 + (( 64 + cb) ^ sw));   \
    }                                                                    \
  } while (0)

#define MFMA_Q(q, AF) do {                                               \
    _Pragma("unroll")                                                    \
    for (int ks = 0; ks < 2; ++ks)                                       \
      _Pragma("unroll")                                                  \
      for (int m2 = 0; m2 < 2; ++m2)                                     \
        _Pragma("unroll")                                                \
        for (int n = 0; n < 4; ++n)                                      \
          acc[(q)*2+m2][n] = __builtin_amdgcn_mfma_f32_16x16x32_bf16(AF[m2][ks], bfr[n][ks], acc[(q)*2+m2][n], 0, 0, 0); \
  } while (0)

  for (int t = 0; t < 36; ++t) {
    char* Abuf = ldsc + ((t & 1) << 16);
    char* Bbuf = Abuf + 32768;
    const int tt = t + 1, pos = tt >> 2, kh = pos/3;
    const int sb1 = (kh*HP + (pos - kh*3))*IC + ((tt & 3) << 6);

    // tile-start reads: B frags + A[q0]; A[q1] one ahead
    #pragma unroll
    for (int n = 0; n < 4; ++n) {
      int rr = rB + n*16, sw = (rr & 7) << 4;
      bfr[n][0] = *(const bf16x8*)(Bbuf + rr*128 + ((  0 + cb) ^ sw));
      bfr[n][1] = *(const bf16x8*)(Bbuf + rr*128 + (( 64 + cb) ^ sw));
    }
    READ_A_TO(af0, 0);
    READ_A_TO(af1, 1);
    if (t < 35) { STAGE_A(tt, 0); STAGE_B(tt, 0, sb1); }

    MFMA_Q(0, af0);                 // af0/bfr waited via partial lgkm
    READ_A_TO(af0, 2);              // service hides under q1's MFMAs
    if (t < 35) { STAGE_A(tt, 1); STAGE_B(tt, 1, sb1); }

    MFMA_Q(1, af1);
    READ_A_TO(af1, 3);              // service hides under q2's MFMAs

    MFMA_Q(2, af0);
    MFMA_Q(3, af1);

    __syncthreads();                // single sync: fence + barrier + drains
  }

  // ---- epilogue: f32 stores, 16-lane 64B segments
  float* outb = out + (((long)b*OC + wr*128 + ((lane >> 4) << 2))*(Hh*Ww))
                    + hwBase + wc*64 + (lane & 15);
  #pragma unroll
  for (int m = 0; m < 8; ++m)
    #pragma unroll
    for (int n = 0; n < 4; ++n)
      #pragma unroll
      for (int j = 0; j < 4; ++j)
        outb[((long)(m*16 + j))*(Hh*Ww) + n*16] = acc[m][n][j];
}

extern "C" void kernel_launch(void* const* d_in, const int* in_sizes, int n_in,
                              void* d_out, int out_size, void* d_ws, size_t ws_size,
                              hipStream_t stream) {
  const float* image = (const float*)d_in[0];
  const float* style = (const float*)d_in[1];
  const float* weight= (const float*)d_in[2];
  const float* modw  = (const float*)d_in[3];
  float* out = (float*)d_out;

  char* ws = (char*)d_ws;
  __bf16* xt   = (__bf16*)ws;
  __bf16* wmat = (__bf16*)(ws + WMAT_OFF);
  float*  sbuf = (float*)(ws + S_OFF);

  k_prep<<<272, 256, 0, stream>>>(weight, style, modw, wmat, sbuf);
  k_xmod<<<Bb*256 + Bb, 256, 0, stream>>>(image, sbuf, xt);
  k_conv<<<256, 512, 0, stream>>>(wmat, xt, out);
}